// Round 14
// baseline (389.324 us; speedup 1.0000x reference)
//
#include <hip/hip_runtime.h>

#define NN 2
#define CC 32
#define NCC 4
#define DD 96
#define WW 96
#define HH 96
#define PP (DD*WW*HH)          // 884736
#define NCP (NN*NCC*PP)        // 7077888
#define SD (WW*HH)             // 9216
#define SW HH                  // 96
#define NCH (PP/1024)          // 864 pooldots chunks per n
#define PB  (PP/1024)          // 864 attn blocks per n
#define EPS 1e-5f
#define BIGF 1e30f

__device__ __forceinline__ float wave_reduce(float v) {
#pragma unroll
    for (int off = 32; off > 0; off >>= 1) v += __shfl_down(v, off, 64);
    return v;
}

__device__ __forceinline__ float dot4(float4 a, float4 b) {
    return a.x*b.x + a.y*b.y + a.z*b.z + a.w*b.w;
}

__device__ __forceinline__ float sigf(float v) { return 1.f / (1.f + __expf(-v)); }

__device__ __forceinline__ void max4v(float4& x, const float* p) {
    float4 a = *(const float4*)p;
    x.x = fmaxf(x.x, a.x); x.y = fmaxf(x.y, a.y);
    x.z = fmaxf(x.z, a.z); x.w = fmaxf(x.w, a.w);
}

__device__ __forceinline__ void min4v(float4& x, const float* p) {
    float4 a = *(const float4*)p;
    x.x = fminf(x.x, a.x); x.y = fminf(x.y, a.y);
    x.z = fminf(x.z, a.z); x.w = fminf(x.w, a.w);
}

// ---- K1: fused sigmoid + 1-D max pool along H. Writes mask + maxH only. ----
__global__ __launch_bounds__(256) void k_poolH(const float* __restrict__ x,
                                               float* __restrict__ mask,
                                               float* __restrict__ omax) {
    int i = (blockIdx.x * 256 + threadIdx.x) * 4;
    int h0 = i % HH;                       // multiple of 4
    float4 xv = *(const float4*)(x + i);
    float v0 = sigf(xv.x), v1 = sigf(xv.y), v2 = sigf(xv.z), v3 = sigf(xv.w);
    float aM = -BIGF, bM = -BIGF, cM = -BIGF, dM = -BIGF;
    if (h0 > 0)  { aM = sigf(x[i-2]); bM = sigf(x[i-1]); }
    if (h0 < 92) { cM = sigf(x[i+4]); dM = sigf(x[i+5]); }
    float4 mo = make_float4(v0, v1, v2, v3), mx;
    mx.x = fmaxf(fmaxf(aM, bM), fmaxf(fmaxf(v0, v1), v2));
    mx.y = fmaxf(bM, fmaxf(fmaxf(v0, v1), fmaxf(v2, v3)));
    mx.z = fmaxf(fmaxf(fmaxf(v0, v1), fmaxf(v2, v3)), cM);
    mx.w = fmaxf(fmaxf(v1, v2), fmaxf(v3, fmaxf(cM, dM)));
    *(float4*)(mask + i) = mo;
    *(float4*)(omax + i) = mx;
}

// ---- K2: fused W+D pools + feat dots, wave-owns-8c structure.
//      Block = 1024 p, 256 thr / 4 waves. Pool once (thread = 4 p,
//      ero/dil -> 32 KB LDS, no reg carry). Dot: wave wv owns c in
//      [8wv, 8wv+8), covers all 1024 p; 72+8 reduces/wave (was 288+8). ----
__global__ __launch_bounds__(256) void k_pooldots(const float* __restrict__ t0,
                                                  const float* __restrict__ mask,
                                                  const float* __restrict__ feat,
                                                  float* __restrict__ dotp) {
    __shared__ __align__(16) float sE[NCC][1024];  // 16 KB ero
    __shared__ __align__(16) float sD[NCC][1024];  // 16 KB dil
    __shared__ float sacc[296];
    __shared__ float swp[4][8];
    int b = blockIdx.x;
    int n = b / NCH;
    int base = (b % NCH) * 1024;
    int t = threadIdx.x;
    int wv = t >> 6, ln = t & 63;
    int pt = base + t * 4;
    int d  = pt / SD;
    int w  = (pt / SW) % WW;
    int h0 = pt % HH;                      // in {0,4,...,92}; 4 p share one row

    float th_e[NCC], th_d[NCC];
#pragma unroll
    for (int k = 0; k < NCC; ++k) {
        const size_t off = (size_t)(n*NCC + k)*PP + pt;
        // dil = max over (dd,ww) in [-2,2]^2 of maxH
        float4 mx = make_float4(-BIGF,-BIGF,-BIGF,-BIGF);
#pragma unroll
        for (int dd = -2; dd <= 2; ++dd) {
            if ((unsigned)(d + dd) < DD) {
#pragma unroll
                for (int ww = -2; ww <= 2; ++ww) {
                    if ((unsigned)(w + ww) < WW)
                        max4v(mx, t0 + off + dd*SD + ww*SW);
                }
            }
        }
        // ero = min(minH, minW, minD) of mask
        float4 m0 = *(const float4*)(mask + off);
        float l0 = BIGF, l1 = BIGF, r0 = BIGF, r1 = BIGF;
        if (h0 > 0)  { l0 = mask[off-2]; l1 = mask[off-1]; }
        if (h0 < 92) { r0 = mask[off+4]; r1 = mask[off+5]; }
        float4 mn;
        mn.x = fminf(fminf(l0, l1),  fminf(m0.x, fminf(m0.y, m0.z)));
        mn.y = fminf(l1, fminf(fminf(m0.x, m0.y), fminf(m0.z, m0.w)));
        mn.z = fminf(fminf(m0.x, m0.y), fminf(m0.z, fminf(m0.w, r0)));
        mn.w = fminf(fminf(m0.y, m0.z), fminf(m0.w, fminf(r0, r1)));
        if (w >= 2)     min4v(mn, mask + off - 2*SW);
        if (w >= 1)     min4v(mn, mask + off -   SW);
        if (w + 1 < WW) min4v(mn, mask + off +   SW);
        if (w + 2 < WW) min4v(mn, mask + off + 2*SW);
        if (d >= 2)     min4v(mn, mask + off - 2*SD);
        if (d >= 1)     min4v(mn, mask + off -   SD);
        if (d + 1 < DD) min4v(mn, mask + off +   SD);
        if (d + 2 < DD) min4v(mn, mask + off + 2*SD);

        *(float4*)&sE[k][t*4] = mn;        // store immediately, no reg carry
        *(float4*)&sD[k][t*4] = mx;
        th_e[k] = mn.x + mn.y + mn.z + mn.w;
        th_d[k] = mx.x + mx.y + mx.z + mx.w;
    }
#pragma unroll
    for (int k = 0; k < NCC; ++k) { th_e[k] = wave_reduce(th_e[k]); th_d[k] = wave_reduce(th_d[k]); }
    if (ln == 0) {
#pragma unroll
        for (int k = 0; k < NCC; ++k) { swp[wv][k] = th_e[k]; swp[wv][4+k] = th_d[k]; }
    }
    __syncthreads();                       // pool LDS ready; swp ready
    if (t < 8) sacc[288 + t] = swp[0][t] + swp[1][t] + swp[2][t] + swp[3][t];

    // ---- dots: wave wv owns 8 channels over all 1024 p ----
    const float* pf = feat + ((size_t)(n*CC) + wv*8)*PP + base;
    for (int cl = 0; cl < 8; ++cl) {
        float a[9];
#pragma unroll
        for (int q = 0; q < 9; ++q) a[q] = 0.f;
#pragma unroll
        for (int j = 0; j < 4; ++j) {
            int po = j*256 + ln*4;
            float4 fv = *(const float4*)(pf + (size_t)cl*PP + po);
#pragma unroll
            for (int k = 0; k < NCC; ++k) {
                float4 e4 = *(const float4*)&sE[k][po];
                float4 d4 = *(const float4*)&sD[k][po];
                a[k]     += dot4(fv, e4);
                a[4 + k] += dot4(fv, d4);
            }
            a[8] += fv.x + fv.y + fv.z + fv.w;
        }
#pragma unroll
        for (int q = 0; q < 9; ++q) {
            float r = wave_reduce(a[q]);
            if (ln == 0) sacc[(wv*8 + cl)*9 + q] = r;   // disjoint per wave
        }
    }
    __syncthreads();
    for (int i = t; i < 296; i += 256)
        dotp[(size_t)b*296 + i] = sacc[i];
}

// ---- K3: stage-1 reduce of partials: 864 chunks -> 27 groups of 32. ----
__global__ __launch_bounds__(320) void k_dotred1(const float* __restrict__ dotp,
                                                 float* __restrict__ dotp2) {
    int t = threadIdx.x;
    if (t >= 296) return;
    int g = blockIdx.x;            // [0, NN*27)
    int n = g / 27, gg = g % 27;
    const float* p = dotp + (size_t)(n*NCH + gg*32)*296 + t;
    float s = 0.f;
#pragma unroll
    for (int j = 0; j < 32; ++j) s += p[(size_t)j*296];
    dotp2[(size_t)g*296 + t] = s;
}

// ---- K4: stage-2 reduce + cluster. grid = NN. ----
__global__ __launch_bounds__(320) void k_dotred2c(const float* __restrict__ dotp2,
                                                  float* __restrict__ cluster) {
    __shared__ float vals[296];
    int t = threadIdx.x;
    int n = blockIdx.x;
    if (t < 296) {
        float s = 0.f;
#pragma unroll
        for (int g = 0; g < 27; ++g) s += dotp2[((size_t)n*27 + g)*296 + t];
        vals[t] = s;
    }
    __syncthreads();
    if (t < NCC*CC) {
        int k = t >> 5, c = t & 31;
        float de = vals[c*9 + k];
        float dd = vals[c*9 + 4 + k];
        float fs = vals[c*9 + 8];
        float es = vals[288 + k] + EPS;
        float ds = vals[292 + k] + EPS;
        float bs = (float)PP - vals[292 + k] + EPS;
        cluster[((n*NCC + k)*CC + c)*2 + 0] = de/es + dd/ds;
        cluster[((n*NCC + k)*CC + c)*2 + 1] = (fs - dd)/bs;
    }
}

// ---- K5: attention BN-stats. Stores w0 weights; wave-private BN slots. ----
__global__ __launch_bounds__(256) void k_attn_stats(const float* __restrict__ feat,
                                                    const float* __restrict__ cluster,
                                                    const float* __restrict__ kptr,
                                                    float* __restrict__ w0a,
                                                    float* __restrict__ bnpart) {
    __shared__ float cl[NCC*CC*2];        // 256
    __shared__ float swp[4][CC*2];        // wave-private BN slots
    int b = blockIdx.x;
    int n = b / PB;
    int p0 = (b % PB) * 1024 + (threadIdx.x << 2);
    int wv = threadIdx.x >> 6, ln = threadIdx.x & 63;
    cl[threadIdx.x] = cluster[n*(NCC*CC*2) + threadIdx.x];
    __syncthreads();

    const float* fb = feat + (size_t)n*CC*PP + p0;

    float4 s0[NCC], s1[NCC];
#pragma unroll
    for (int k = 0; k < NCC; ++k) {
        s0[k] = make_float4(0.f, 0.f, 0.f, 0.f);
        s1[k] = make_float4(0.f, 0.f, 0.f, 0.f);
    }
    float4 fv = *(const float4*)fb;
    for (int c = 0; c < CC; ++c) {
        int cn = (c + 1 < CC) ? (c + 1) : c;
        float4 nv = *(const float4*)(fb + (size_t)cn*PP);
#pragma unroll
        for (int k = 0; k < NCC; ++k) {
            float2 cc2 = *(const float2*)&cl[(k*CC + c)*2];
            s0[k].x += fv.x*cc2.x; s0[k].y += fv.y*cc2.x;
            s0[k].z += fv.z*cc2.x; s0[k].w += fv.w*cc2.x;
            s1[k].x += fv.x*cc2.y; s1[k].y += fv.y*cc2.y;
            s1[k].z += fv.z*cc2.y; s1[k].w += fv.w*cc2.y;
        }
        fv = nv;
    }
    // softmax over 2 logits: w0 = sigmoid(s0-s1); store for apply pass
    float4 w0[NCC], w1[NCC];
#pragma unroll
    for (int k = 0; k < NCC; ++k) {
        w0[k].x = 1.f/(1.f + __expf(s1[k].x - s0[k].x));
        w0[k].y = 1.f/(1.f + __expf(s1[k].y - s0[k].y));
        w0[k].z = 1.f/(1.f + __expf(s1[k].z - s0[k].z));
        w0[k].w = 1.f/(1.f + __expf(s1[k].w - s0[k].w));
        w1[k].x = 1.f - w0[k].x; w1[k].y = 1.f - w0[k].y;
        w1[k].z = 1.f - w0[k].z; w1[k].w = 1.f - w0[k].w;
        *(float4*)(w0a + (size_t)(n*NCC + k)*PP + p0) = w0[k];
    }

    float kk = kptr[0];
#pragma unroll 8
    for (int c = 0; c < CC; ++c) {
        float4 f2 = *(const float4*)(fb + (size_t)c*PP);   // L2-hit re-read
        float4 a = make_float4(0.f, 0.f, 0.f, 0.f);
#pragma unroll
        for (int k = 0; k < NCC; ++k) {
            float2 cc2 = *(const float2*)&cl[(k*CC + c)*2];
            a.x += w0[k].x*cc2.x + w1[k].x*cc2.y;
            a.y += w0[k].y*cc2.x + w1[k].y*cc2.y;
            a.z += w0[k].z*cc2.x + w1[k].z*cc2.y;
            a.w += w0[k].w*cc2.x + w1[k].w*cc2.y;
        }
        float4 o;
        o.x = 5.f*f2.x + kk*a.x; o.y = 5.f*f2.y + kk*a.y;
        o.z = 5.f*f2.z + kk*a.z; o.w = 5.f*f2.w + kk*a.w;
        float ls = o.x + o.y + o.z + o.w;
        float lq = o.x*o.x + o.y*o.y + o.z*o.z + o.w*o.w;
        ls = wave_reduce(ls);
        lq = wave_reduce(lq);
        if (ln == 0) { swp[wv][2*c] = ls; swp[wv][2*c + 1] = lq; }
    }
    __syncthreads();
    if (threadIdx.x < CC*2)
        bnpart[(size_t)b*(CC*2) + threadIdx.x] =
            swp[0][threadIdx.x] + swp[1][threadIdx.x] +
            swp[2][threadIdx.x] + swp[3][threadIdx.x];
}

// ---- K6: reduce BN partials -> scale/shift. grid = CC blocks. ----
__global__ __launch_bounds__(256) void k_bnred(const float* __restrict__ bnpart,
                                               const float* __restrict__ wgt,
                                               const float* __restrict__ bias,
                                               float* __restrict__ scale,
                                               float* __restrict__ shift) {
    int c = blockIdx.x;
    float s = 0.f, q = 0.f;
    for (int b = threadIdx.x; b < NN*PB; b += 256) {
        s += bnpart[(size_t)b*(CC*2) + c*2];
        q += bnpart[(size_t)b*(CC*2) + c*2 + 1];
    }
    s = wave_reduce(s); q = wave_reduce(q);
    __shared__ float a[4], bb[4];
    if ((threadIdx.x & 63) == 0) { a[threadIdx.x >> 6] = s; bb[threadIdx.x >> 6] = q; }
    __syncthreads();
    if (threadIdx.x == 0) {
        float ts = a[0]+a[1]+a[2]+a[3];
        float tq = bb[0]+bb[1]+bb[2]+bb[3];
        float inv_n = 1.f / (float)((size_t)NN * PP);
        float mean = ts * inv_n;
        float var  = tq * inv_n - mean*mean;
        float inv  = 1.f / sqrtf(var + EPS);
        float sc = wgt[c] * inv;
        scale[c] = sc;
        shift[c] = bias[c] - mean*sc;
    }
}

// ---- K7: attention apply. Reads stored w0 — NO logit recompute. ----
__global__ __launch_bounds__(256) void k_attn_apply(const float* __restrict__ feat,
                                                    const float* __restrict__ w0a,
                                                    const float* __restrict__ cluster,
                                                    const float* __restrict__ kptr,
                                                    const float* __restrict__ scale,
                                                    const float* __restrict__ shift,
                                                    float* __restrict__ out) {
    __shared__ float cl[NCC*CC*2];
    __shared__ float ssc[CC], ssh[CC];
    int b = blockIdx.x;
    int n = b / PB;
    int p0 = (b % PB) * 1024 + (threadIdx.x << 2);
    cl[threadIdx.x] = cluster[n*(NCC*CC*2) + threadIdx.x];
    if (threadIdx.x < CC) {
        ssc[threadIdx.x] = scale[threadIdx.x];
        ssh[threadIdx.x] = shift[threadIdx.x];
    }
    __syncthreads();

    float4 w0[NCC], w1[NCC];
#pragma unroll
    for (int k = 0; k < NCC; ++k) {
        w0[k] = *(const float4*)(w0a + (size_t)(n*NCC + k)*PP + p0);
        w1[k].x = 1.f - w0[k].x; w1[k].y = 1.f - w0[k].y;
        w1[k].z = 1.f - w0[k].z; w1[k].w = 1.f - w0[k].w;
    }

    float kk = kptr[0];
    const float* fb = feat + (size_t)n*CC*PP + p0;
    float* ob = out + (size_t)n*CC*PP + p0;
    float4 fv = *(const float4*)fb;
    for (int c = 0; c < CC; ++c) {
        int cn = (c + 1 < CC) ? (c + 1) : c;
        float4 nv = *(const float4*)(fb + (size_t)cn*PP);
        float4 a = make_float4(0.f, 0.f, 0.f, 0.f);
#pragma unroll
        for (int k = 0; k < NCC; ++k) {
            float2 cc2 = *(const float2*)&cl[(k*CC + c)*2];
            a.x += w0[k].x*cc2.x + w1[k].x*cc2.y;
            a.y += w0[k].y*cc2.x + w1[k].y*cc2.y;
            a.z += w0[k].z*cc2.x + w1[k].z*cc2.y;
            a.w += w0[k].w*cc2.x + w1[k].w*cc2.y;
        }
        float sc = ssc[c], sh = ssh[c];
        float4 o;
        o.x = (5.f*fv.x + kk*a.x)*sc + sh;
        o.y = (5.f*fv.y + kk*a.y)*sc + sh;
        o.z = (5.f*fv.z + kk*a.z)*sc + sh;
        o.w = (5.f*fv.w + kk*a.w)*sc + sh;
        *(float4*)(ob + (size_t)c*PP) = o;
        fv = nv;
    }
}

extern "C" void kernel_launch(void* const* d_in, const int* in_sizes, int n_in,
                              void* d_out, int out_size, void* d_ws, size_t ws_size,
                              hipStream_t stream) {
    const float* feat = (const float*)d_in[0];
    const float* x    = (const float*)d_in[1];
    const float* kp   = (const float*)d_in[2];
    const float* bnw  = (const float*)d_in[3];
    const float* bnb  = (const float*)d_in[4];
    float* out = (float*)d_out;
    float* ws  = (float*)d_ws;

    float* mask    = ws;                         // NCP
    float* t0      = ws + 1*(size_t)NCP;         // NCP (maxH)
    float* w0a     = ws + 2*(size_t)NCP;         // NCP (softmax w0 weights)
    float* scratch = ws + 3*(size_t)NCP;
    float* dotp    = scratch;                    // 1728*296 = 511488
    float* dotp2   = scratch + 524288;           // 54*296  = 15984
    float* bnpart  = scratch + 540672;           // 1728*64 = 110592
    float* acc     = scratch + 655360;
    float* cluster = acc;                        // 512
    float* scale   = acc + 512;                  // 32
    float* shift   = acc + 544;                  // 32

    k_poolH     <<<NCP/1024, 256, 0, stream>>>(x, mask, t0);
    k_pooldots  <<<NN*NCH, 256, 0, stream>>>(t0, mask, feat, dotp);
    k_dotred1   <<<NN*27, 320, 0, stream>>>(dotp, dotp2);
    k_dotred2c  <<<NN, 320, 0, stream>>>(dotp2, cluster);
    k_attn_stats<<<NN*PB, 256, 0, stream>>>(feat, cluster, kp, w0a, bnpart);
    k_bnred     <<<CC, 256, 0, stream>>>(bnpart, bnw, bnb, scale, shift);
    k_attn_apply<<<NN*PB, 256, 0, stream>>>(feat, w0a, cluster, kp, scale, shift, out);
}

// Round 15
// 298.787 us; speedup vs baseline: 1.3030x; 1.3030x over previous
//
#include <hip/hip_runtime.h>

#define NN 2
#define CC 32
#define NCC 4
#define DD 96
#define WW 96
#define HH 96
#define PP (DD*WW*HH)          // 884736
#define NCP (NN*NCC*PP)        // 7077888
#define SD (WW*HH)             // 9216
#define SW HH                  // 96
#define DCH (PP/2048)          // 432 pooldots chunks per n
#define PB  (PP/1024)          // 864 attn blocks per n
#define EPS 1e-5f
#define BIGF 1e30f

// DPP-based full-wave sum: 6 VALU adds, NO DS-pipe traffic (vs ds_bpermute
// from __shfl_down). Result valid in lane 63. old=0 + row_mask => masked
// lanes add 0.  row_shr:N = 0x110|N, row_bcast15 = 0x142, row_bcast31 = 0x143.
__device__ __forceinline__ float wave_reduce(float v) {
    v += __int_as_float(__builtin_amdgcn_update_dpp(0, __float_as_int(v), 0x111, 0xf, 0xf, true));
    v += __int_as_float(__builtin_amdgcn_update_dpp(0, __float_as_int(v), 0x112, 0xf, 0xf, true));
    v += __int_as_float(__builtin_amdgcn_update_dpp(0, __float_as_int(v), 0x114, 0xf, 0xf, true));
    v += __int_as_float(__builtin_amdgcn_update_dpp(0, __float_as_int(v), 0x118, 0xf, 0xf, true));
    v += __int_as_float(__builtin_amdgcn_update_dpp(0, __float_as_int(v), 0x142, 0xa, 0xf, true));
    v += __int_as_float(__builtin_amdgcn_update_dpp(0, __float_as_int(v), 0x143, 0xc, 0xf, true));
    return v;   // lane 63 holds the full 64-lane sum
}

__device__ __forceinline__ float dot8(float4 a0, float4 a1, float4 b0, float4 b1) {
    return a0.x*b0.x + a0.y*b0.y + a0.z*b0.z + a0.w*b0.w
         + a1.x*b1.x + a1.y*b1.y + a1.z*b1.z + a1.w*b1.w;
}

__device__ __forceinline__ float sigf(float v) { return 1.f / (1.f + __expf(-v)); }

__device__ __forceinline__ void max8(float4& x0, float4& x1, const float* p) {
    float4 a = *(const float4*)p, b = *(const float4*)(p + 4);
    x0.x = fmaxf(x0.x, a.x); x0.y = fmaxf(x0.y, a.y);
    x0.z = fmaxf(x0.z, a.z); x0.w = fmaxf(x0.w, a.w);
    x1.x = fmaxf(x1.x, b.x); x1.y = fmaxf(x1.y, b.y);
    x1.z = fmaxf(x1.z, b.z); x1.w = fmaxf(x1.w, b.w);
}

__device__ __forceinline__ void min8(float4& x0, float4& x1, const float* p) {
    float4 a = *(const float4*)p, b = *(const float4*)(p + 4);
    x0.x = fminf(x0.x, a.x); x0.y = fminf(x0.y, a.y);
    x0.z = fminf(x0.z, a.z); x0.w = fminf(x0.w, a.w);
    x1.x = fminf(x1.x, b.x); x1.y = fminf(x1.y, b.y);
    x1.z = fminf(x1.z, b.z); x1.w = fminf(x1.w, b.w);
}

// ---- K1: fused sigmoid + 1-D max pool along H. Writes mask + maxH only. ----
__global__ __launch_bounds__(256) void k_poolH(const float* __restrict__ x,
                                               float* __restrict__ mask,
                                               float* __restrict__ omax) {
    int i = (blockIdx.x * 256 + threadIdx.x) * 4;
    int h0 = i % HH;                       // multiple of 4
    float4 xv = *(const float4*)(x + i);
    float v0 = sigf(xv.x), v1 = sigf(xv.y), v2 = sigf(xv.z), v3 = sigf(xv.w);
    float aM = -BIGF, bM = -BIGF, cM = -BIGF, dM = -BIGF;
    if (h0 > 0)  { aM = sigf(x[i-2]); bM = sigf(x[i-1]); }
    if (h0 < 92) { cM = sigf(x[i+4]); dM = sigf(x[i+5]); }
    float4 mo = make_float4(v0, v1, v2, v3), mx;
    mx.x = fmaxf(fmaxf(aM, bM), fmaxf(fmaxf(v0, v1), v2));
    mx.y = fmaxf(bM, fmaxf(fmaxf(v0, v1), fmaxf(v2, v3)));
    mx.z = fmaxf(fmaxf(fmaxf(v0, v1), fmaxf(v2, v3)), cM);
    mx.w = fmaxf(fmaxf(v1, v2), fmaxf(v3, fmaxf(cM, dM)));
    *(float4*)(mask + i) = mo;
    *(float4*)(omax + i) = mx;
}

// ---- K2: fused W+D pools + feat dots (R13 structure: 256 thr, 8 p/thread,
//      25-tap dil, prefetch, wave-private slots; DPP reduce, lane-63 write). ----
__global__ __launch_bounds__(256, 2) void k_pooldots(const float* __restrict__ t0,
                                                     const float* __restrict__ mask,
                                                     const float* __restrict__ feat,
                                                     float* __restrict__ dotp) {
    int b = blockIdx.x;
    int n = b / DCH;
    int pt = (b % DCH) * 2048 + threadIdx.x * 8;   // intra-n offset; 8 | 96
    int d  = pt / SD;
    int w  = (pt / SW) % WW;
    int h0 = pt % HH;                              // in {0,8,...,88}
    int wv = threadIdx.x >> 6, ln = threadIdx.x & 63;

    __shared__ float sacc[4][296];                 // per-wave slots: no atomics

    float4 e[NCC][2], dv[NCC][2];
#pragma unroll
    for (int k = 0; k < NCC; ++k) {
        const size_t off = (size_t)(n*NCC + k)*PP + pt;
        // dil = max over (dd,ww) in [-2,2]^2 of maxH
        float4 mx0 = make_float4(-BIGF,-BIGF,-BIGF,-BIGF), mx1 = mx0;
#pragma unroll
        for (int dd = -2; dd <= 2; ++dd) {
            if ((unsigned)(d + dd) < DD) {
#pragma unroll
                for (int ww = -2; ww <= 2; ++ww) {
                    if ((unsigned)(w + ww) < WW)
                        max8(mx0, mx1, t0 + off + dd*SD + ww*SW);
                }
            }
        }
        // ero = min(minH, minW, minD) of mask
        float4 m0 = *(const float4*)(mask + off);
        float4 m1 = *(const float4*)(mask + off + 4);
        float l0 = BIGF, l1 = BIGF, r0 = BIGF, r1 = BIGF;
        if (h0 > 0)  { l0 = mask[off-2]; l1 = mask[off-1]; }
        if (h0 < 88) { r0 = mask[off+8]; r1 = mask[off+9]; }
        float mv0=l0, mv1=l1, mv2=m0.x, mv3=m0.y, mv4=m0.z, mv5=m0.w,
              mv6=m1.x, mv7=m1.y, mv8=m1.z, mv9=m1.w, mv10=r0, mv11=r1;
        float4 mn0, mn1;
        mn0.x = fminf(fminf(mv0,mv1), fminf(mv2, fminf(mv3,mv4)));
        mn0.y = fminf(fminf(mv1,mv2), fminf(mv3, fminf(mv4,mv5)));
        mn0.z = fminf(fminf(mv2,mv3), fminf(mv4, fminf(mv5,mv6)));
        mn0.w = fminf(fminf(mv3,mv4), fminf(mv5, fminf(mv6,mv7)));
        mn1.x = fminf(fminf(mv4,mv5), fminf(mv6, fminf(mv7,mv8)));
        mn1.y = fminf(fminf(mv5,mv6), fminf(mv7, fminf(mv8,mv9)));
        mn1.z = fminf(fminf(mv6,mv7), fminf(mv8, fminf(mv9,mv10)));
        mn1.w = fminf(fminf(mv7,mv8), fminf(mv9, fminf(mv10,mv11)));
        if (w >= 2)     min8(mn0, mn1, mask + off - 2*SW);
        if (w >= 1)     min8(mn0, mn1, mask + off -   SW);
        if (w + 1 < WW) min8(mn0, mn1, mask + off +   SW);
        if (w + 2 < WW) min8(mn0, mn1, mask + off + 2*SW);
        if (d >= 2)     min8(mn0, mn1, mask + off - 2*SD);
        if (d >= 1)     min8(mn0, mn1, mask + off -   SD);
        if (d + 1 < DD) min8(mn0, mn1, mask + off +   SD);
        if (d + 2 < DD) min8(mn0, mn1, mask + off + 2*SD);

        e[k][0] = mn0; e[k][1] = mn1;
        dv[k][0] = mx0; dv[k][1] = mx1;
        float th_e = mn0.x+mn0.y+mn0.z+mn0.w + mn1.x+mn1.y+mn1.z+mn1.w;
        float th_d = mx0.x+mx0.y+mx0.z+mx0.w + mx1.x+mx1.y+mx1.z+mx1.w;
        th_e = wave_reduce(th_e);
        th_d = wave_reduce(th_d);
        if (ln == 63) {
            sacc[wv][288 + k] = th_e;
            sacc[wv][292 + k] = th_d;
        }
    }

    // feat dots, depth-1 prefetch
    const float* pf = feat + (size_t)(n*CC)*PP + pt;
    float4 fa = *(const float4*)pf;
    float4 fb = *(const float4*)(pf + 4);
    for (int c = 0; c < CC; ++c) {
        int cn = (c + 1 < CC) ? (c + 1) : c;
        const float* pn = pf + (size_t)cn*PP;
        float4 na = *(const float4*)pn;
        float4 nb = *(const float4*)(pn + 4);
        float vals[9];
#pragma unroll
        for (int k = 0; k < NCC; ++k) {
            vals[k]     = dot8(fa, fb, e[k][0],  e[k][1]);
            vals[4 + k] = dot8(fa, fb, dv[k][0], dv[k][1]);
        }
        vals[8] = fa.x+fa.y+fa.z+fa.w + fb.x+fb.y+fb.z+fb.w;
#pragma unroll
        for (int q = 0; q < 9; ++q) {
            float r = wave_reduce(vals[q]);
            if (ln == 63) sacc[wv][c*9 + q] = r;
        }
        fa = na; fb = nb;
    }
    __syncthreads();
    for (int t = threadIdx.x; t < 296; t += 256)
        dotp[(size_t)b*296 + t] = sacc[0][t] + sacc[1][t] + sacc[2][t] + sacc[3][t];
}

// ---- K3: stage-1 reduce of partials: 432 chunks -> 27 groups of 16. ----
__global__ __launch_bounds__(320) void k_dotred1(const float* __restrict__ dotp,
                                                 float* __restrict__ dotp2) {
    int t = threadIdx.x;
    if (t >= 296) return;
    int g = blockIdx.x;            // [0, NN*27)
    int n = g / 27, gg = g % 27;
    const float* p = dotp + (size_t)(n*DCH + gg*16)*296 + t;
    float s = 0.f;
#pragma unroll
    for (int j = 0; j < 16; ++j) s += p[(size_t)j*296];
    dotp2[(size_t)g*296 + t] = s;
}

// ---- K4: stage-2 reduce + cluster. grid = NN. ----
__global__ __launch_bounds__(320) void k_dotred2c(const float* __restrict__ dotp2,
                                                  float* __restrict__ cluster) {
    __shared__ float vals[296];
    int t = threadIdx.x;
    int n = blockIdx.x;
    if (t < 296) {
        float s = 0.f;
#pragma unroll
        for (int g = 0; g < 27; ++g) s += dotp2[((size_t)n*27 + g)*296 + t];
        vals[t] = s;
    }
    __syncthreads();
    if (t < NCC*CC) {
        int k = t >> 5, c = t & 31;
        float de = vals[c*9 + k];
        float dd = vals[c*9 + 4 + k];
        float fs = vals[c*9 + 8];
        float es = vals[288 + k] + EPS;
        float ds = vals[292 + k] + EPS;
        float bs = (float)PP - vals[292 + k] + EPS;
        cluster[((n*NCC + k)*CC + c)*2 + 0] = de/es + dd/ds;
        cluster[((n*NCC + k)*CC + c)*2 + 1] = (fs - dd)/bs;
    }
}

// ---- K5: attention BN-stats. Stores w0 weights; wave-private BN slots;
//      DPP reduce, lane-63 write. ----
__global__ __launch_bounds__(256) void k_attn_stats(const float* __restrict__ feat,
                                                    const float* __restrict__ cluster,
                                                    const float* __restrict__ kptr,
                                                    float* __restrict__ w0a,
                                                    float* __restrict__ bnpart) {
    __shared__ float cl[NCC*CC*2];        // 256
    __shared__ float swp[4][CC*2];        // wave-private BN slots
    int b = blockIdx.x;
    int n = b / PB;
    int p0 = (b % PB) * 1024 + (threadIdx.x << 2);
    int wv = threadIdx.x >> 6, ln = threadIdx.x & 63;
    cl[threadIdx.x] = cluster[n*(NCC*CC*2) + threadIdx.x];
    __syncthreads();

    const float* fb = feat + (size_t)n*CC*PP + p0;

    float4 s0[NCC], s1[NCC];
#pragma unroll
    for (int k = 0; k < NCC; ++k) {
        s0[k] = make_float4(0.f, 0.f, 0.f, 0.f);
        s1[k] = make_float4(0.f, 0.f, 0.f, 0.f);
    }
    float4 fv = *(const float4*)fb;
    for (int c = 0; c < CC; ++c) {
        int cn = (c + 1 < CC) ? (c + 1) : c;
        float4 nv = *(const float4*)(fb + (size_t)cn*PP);
#pragma unroll
        for (int k = 0; k < NCC; ++k) {
            float2 cc2 = *(const float2*)&cl[(k*CC + c)*2];
            s0[k].x += fv.x*cc2.x; s0[k].y += fv.y*cc2.x;
            s0[k].z += fv.z*cc2.x; s0[k].w += fv.w*cc2.x;
            s1[k].x += fv.x*cc2.y; s1[k].y += fv.y*cc2.y;
            s1[k].z += fv.z*cc2.y; s1[k].w += fv.w*cc2.y;
        }
        fv = nv;
    }
    // softmax over 2 logits: w0 = sigmoid(s0-s1); store for apply pass
    float4 w0[NCC], w1[NCC];
#pragma unroll
    for (int k = 0; k < NCC; ++k) {
        w0[k].x = 1.f/(1.f + __expf(s1[k].x - s0[k].x));
        w0[k].y = 1.f/(1.f + __expf(s1[k].y - s0[k].y));
        w0[k].z = 1.f/(1.f + __expf(s1[k].z - s0[k].z));
        w0[k].w = 1.f/(1.f + __expf(s1[k].w - s0[k].w));
        w1[k].x = 1.f - w0[k].x; w1[k].y = 1.f - w0[k].y;
        w1[k].z = 1.f - w0[k].z; w1[k].w = 1.f - w0[k].w;
        *(float4*)(w0a + (size_t)(n*NCC + k)*PP + p0) = w0[k];
    }

    float kk = kptr[0];
#pragma unroll 8
    for (int c = 0; c < CC; ++c) {
        float4 f2 = *(const float4*)(fb + (size_t)c*PP);   // L2-hit re-read
        float4 a = make_float4(0.f, 0.f, 0.f, 0.f);
#pragma unroll
        for (int k = 0; k < NCC; ++k) {
            float2 cc2 = *(const float2*)&cl[(k*CC + c)*2];
            a.x += w0[k].x*cc2.x + w1[k].x*cc2.y;
            a.y += w0[k].y*cc2.x + w1[k].y*cc2.y;
            a.z += w0[k].z*cc2.x + w1[k].z*cc2.y;
            a.w += w0[k].w*cc2.x + w1[k].w*cc2.y;
        }
        float4 o;
        o.x = 5.f*f2.x + kk*a.x; o.y = 5.f*f2.y + kk*a.y;
        o.z = 5.f*f2.z + kk*a.z; o.w = 5.f*f2.w + kk*a.w;
        float ls = o.x + o.y + o.z + o.w;
        float lq = o.x*o.x + o.y*o.y + o.z*o.z + o.w*o.w;
        ls = wave_reduce(ls);
        lq = wave_reduce(lq);
        if (ln == 63) { swp[wv][2*c] = ls; swp[wv][2*c + 1] = lq; }
    }
    __syncthreads();
    if (threadIdx.x < CC*2)
        bnpart[(size_t)b*(CC*2) + threadIdx.x] =
            swp[0][threadIdx.x] + swp[1][threadIdx.x] +
            swp[2][threadIdx.x] + swp[3][threadIdx.x];
}

// ---- K6: reduce BN partials -> scale/shift. grid = CC blocks. ----
__global__ __launch_bounds__(256) void k_bnred(const float* __restrict__ bnpart,
                                               const float* __restrict__ wgt,
                                               const float* __restrict__ bias,
                                               float* __restrict__ scale,
                                               float* __restrict__ shift) {
    int c = blockIdx.x;
    float s = 0.f, q = 0.f;
    for (int b = threadIdx.x; b < NN*PB; b += 256) {
        s += bnpart[(size_t)b*(CC*2) + c*2];
        q += bnpart[(size_t)b*(CC*2) + c*2 + 1];
    }
    s = wave_reduce(s); q = wave_reduce(q);
    __shared__ float a[4], bb[4];
    if ((threadIdx.x & 63) == 63) { a[threadIdx.x >> 6] = s; bb[threadIdx.x >> 6] = q; }
    __syncthreads();
    if (threadIdx.x == 0) {
        float ts = a[0]+a[1]+a[2]+a[3];
        float tq = bb[0]+bb[1]+bb[2]+bb[3];
        float inv_n = 1.f / (float)((size_t)NN * PP);
        float mean = ts * inv_n;
        float var  = tq * inv_n - mean*mean;
        float inv  = 1.f / sqrtf(var + EPS);
        float sc = wgt[c] * inv;
        scale[c] = sc;
        shift[c] = bias[c] - mean*sc;
    }
}

// ---- K7: attention apply. Reads stored w0 — NO logit recompute. ----
__global__ __launch_bounds__(256) void k_attn_apply(const float* __restrict__ feat,
                                                    const float* __restrict__ w0a,
                                                    const float* __restrict__ cluster,
                                                    const float* __restrict__ kptr,
                                                    const float* __restrict__ scale,
                                                    const float* __restrict__ shift,
                                                    float* __restrict__ out) {
    __shared__ float cl[NCC*CC*2];
    __shared__ float ssc[CC], ssh[CC];
    int b = blockIdx.x;
    int n = b / PB;
    int p0 = (b % PB) * 1024 + (threadIdx.x << 2);
    cl[threadIdx.x] = cluster[n*(NCC*CC*2) + threadIdx.x];
    if (threadIdx.x < CC) {
        ssc[threadIdx.x] = scale[threadIdx.x];
        ssh[threadIdx.x] = shift[threadIdx.x];
    }
    __syncthreads();

    float4 w0[NCC], w1[NCC];
#pragma unroll
    for (int k = 0; k < NCC; ++k) {
        w0[k] = *(const float4*)(w0a + (size_t)(n*NCC + k)*PP + p0);
        w1[k].x = 1.f - w0[k].x; w1[k].y = 1.f - w0[k].y;
        w1[k].z = 1.f - w0[k].z; w1[k].w = 1.f - w0[k].w;
    }

    float kk = kptr[0];
    const float* fb = feat + (size_t)n*CC*PP + p0;
    float* ob = out + (size_t)n*CC*PP + p0;
    float4 fv = *(const float4*)fb;
    for (int c = 0; c < CC; ++c) {
        int cn = (c + 1 < CC) ? (c + 1) : c;
        float4 nv = *(const float4*)(fb + (size_t)cn*PP);
        float4 a = make_float4(0.f, 0.f, 0.f, 0.f);
#pragma unroll
        for (int k = 0; k < NCC; ++k) {
            float2 cc2 = *(const float2*)&cl[(k*CC + c)*2];
            a.x += w0[k].x*cc2.x + w1[k].x*cc2.y;
            a.y += w0[k].y*cc2.x + w1[k].y*cc2.y;
            a.z += w0[k].z*cc2.x + w1[k].z*cc2.y;
            a.w += w0[k].w*cc2.x + w1[k].w*cc2.y;
        }
        float sc = ssc[c], sh = ssh[c];
        float4 o;
        o.x = (5.f*fv.x + kk*a.x)*sc + sh;
        o.y = (5.f*fv.y + kk*a.y)*sc + sh;
        o.z = (5.f*fv.z + kk*a.z)*sc + sh;
        o.w = (5.f*fv.w + kk*a.w)*sc + sh;
        *(float4*)(ob + (size_t)c*PP) = o;
        fv = nv;
    }
}

extern "C" void kernel_launch(void* const* d_in, const int* in_sizes, int n_in,
                              void* d_out, int out_size, void* d_ws, size_t ws_size,
                              hipStream_t stream) {
    const float* feat = (const float*)d_in[0];
    const float* x    = (const float*)d_in[1];
    const float* kp   = (const float*)d_in[2];
    const float* bnw  = (const float*)d_in[3];
    const float* bnb  = (const float*)d_in[4];
    float* out = (float*)d_out;
    float* ws  = (float*)d_ws;

    float* mask    = ws;                         // NCP
    float* t0      = ws + 1*(size_t)NCP;         // NCP (maxH)
    float* w0a     = ws + 2*(size_t)NCP;         // NCP (softmax w0 weights)
    float* scratch = ws + 3*(size_t)NCP;
    float* dotp    = scratch;                    // 864*296 = 255744
    float* dotp2   = scratch + 262144;           // 54*296  = 15984
    float* bnpart  = scratch + 280000;           // 1728*64 = 110592
    float* acc     = scratch + 393216;
    float* cluster = acc;                        // 512
    float* scale   = acc + 512;                  // 32
    float* shift   = acc + 544;                  // 32

    k_poolH     <<<NCP/1024, 256, 0, stream>>>(x, mask, t0);
    k_pooldots  <<<NN*DCH, 256, 0, stream>>>(t0, mask, feat, dotp);
    k_dotred1   <<<NN*27, 320, 0, stream>>>(dotp, dotp2);
    k_dotred2c  <<<NN, 320, 0, stream>>>(dotp2, cluster);
    k_attn_stats<<<NN*PB, 256, 0, stream>>>(feat, cluster, kp, w0a, bnpart);
    k_bnred     <<<CC, 256, 0, stream>>>(bnpart, bnw, bnb, scale, shift);
    k_attn_apply<<<NN*PB, 256, 0, stream>>>(feat, w0a, cluster, kp, scale, shift, out);
}